// Round 5
// baseline (92.504 us; speedup 1.0000x reference)
//
#include <hip/hip_runtime.h>

#define N 512          // n = 2*B
#define B 256
#define D 512
#define NT 512         // block size
#define NBLK (N / 2)   // 256 main blocks, 2 rows each

// ws layout (floats)
#define WS_SL    0          // [N] sorted labels ascending
#define WS_RANK  N          // [N] int rank of original index j
#define WS_SUM   (2 * N)    // [1] float accumulator
#define WS_CNT   (2 * N + 1) // [1] uint ticket

// ---- kernel 1 (grid 16): counting rank of labels + init accumulators ----
__global__ __launch_bounds__(NT) void rank_kernel(
    const float* __restrict__ lwt, const float* __restrict__ lmt,
    float* __restrict__ ws)
{
    const int t = threadIdx.x, b = blockIdx.x;
    __shared__ float slab[N];
    __shared__ int scnt[32];
    slab[t] = (t < B) ? lwt[t] : lmt[t - B];
    if (t < 32) scnt[t] = 0;
    __syncthreads();

    // rank of j = b*32 + (t&31); chunk c = t>>5 covers x in [c*32, c*32+32)
    const int jj = t & 31, j = b * 32 + jj, c = t >> 5;
    const float lj = slab[j];
    int r = 0;
    #pragma unroll 8
    for (int x = c * 32; x < c * 32 + 32; ++x) {
        const float v = slab[x];   // <=2 distinct addrs per wave: conflict-free
        r += (v < lj || (v == lj && x < j)) ? 1 : 0;
    }
    atomicAdd(&scnt[jj], r);
    __syncthreads();
    if (t < 32) {
        const int r2 = scnt[t], j2 = b * 32 + t;
        ws[WS_SL + r2] = slab[j2];
        ((int*)ws)[WS_RANK + j2] = r2;
    }
    if (b == 0 && t == 0) {
        ws[WS_SUM] = 0.f;
        ((unsigned*)ws)[WS_CNT] = 0u;
    }
}

// ---- kernel 2 (grid 256): 2 rows/block, dist + scan + search + finalize ----
__global__ __launch_bounds__(NT) void rnc_main(
    const float* __restrict__ wt, const float* __restrict__ mt,
    const float* __restrict__ lwt, const float* __restrict__ lmt,
    float* __restrict__ ws, float* __restrict__ out)
{
    const int b = blockIdx.x, i0 = 2 * b, i1 = 2 * b + 1;
    const int t = threadIdx.x;
    const int w = t >> 6, lane = t & 63, g = lane >> 4, s = lane & 15;

    __shared__ float sl[N];
    __shared__ int   srk[N];
    __shared__ __align__(16) float sp0[N];   // row0 prefix-scan array
    __shared__ __align__(16) float sf0[N];   // row0 suffix-scan array
    __shared__ __align__(16) float sp1[N];
    __shared__ __align__(16) float sf1[N];
    __shared__ float sred[NT / 64];

    sl[t]  = ws[WS_SL + t];
    srk[t] = ((const int*)ws)[WS_RANK + t];

    // preload rows i0, i1 (32 floats each per lane, chunk = s + 16q)
    const float* Fi0 = (i0 < B) ? (wt + (size_t)i0 * D) : (mt + (size_t)(i0 - B) * D);
    const float* Fi1 = (i1 < B) ? (wt + (size_t)i1 * D) : (mt + (size_t)(i1 - B) * D);
    const float4* Fi04 = (const float4*)Fi0;
    const float4* Fi14 = (const float4*)Fi1;
    float4 fr0[8], fr1[8];
    #pragma unroll
    for (int q = 0; q < 8; ++q) { fr0[q] = Fi04[s + 16 * q]; fr1[q] = Fi14[s + 16 * q]; }
    const float li0 = (i0 < B) ? lwt[i0] : lmt[i0 - B];
    const float li1 = (i1 < B) ? lwt[i1] : lmt[i1 - B];

    // row norms in-register (valid at s==0 of each 16-lane group)
    float ni0 = 0.f, ni1 = 0.f;
    #pragma unroll
    for (int q = 0; q < 8; ++q) {
        ni0 += fr0[q].x * fr0[q].x + fr0[q].y * fr0[q].y
             + fr0[q].z * fr0[q].z + fr0[q].w * fr0[q].w;
        ni1 += fr1[q].x * fr1[q].x + fr1[q].y * fr1[q].y
             + fr1[q].z * fr1[q].z + fr1[q].w * fr1[q].w;
    }
    ni0 += __shfl_down(ni0, 8, 16); ni1 += __shfl_down(ni1, 8, 16);
    ni0 += __shfl_down(ni0, 4, 16); ni1 += __shfl_down(ni1, 4, 16);
    ni0 += __shfl_down(ni0, 2, 16); ni1 += __shfl_down(ni1, 2, 16);
    ni0 += __shfl_down(ni0, 1, 16); ni1 += __shfl_down(ni1, 1, 16);
    __syncthreads();

    // ---- phase 1: Gram-form distances + in-loop norms, scatter e sorted ----
    float lg_acc = 0.f;
    const int wg = w * 4 + g;                 // 0..31
    for (int m = 0; m < 16; ++m) {
        const int j = wg + 32 * m;
        const float* Fj = (j < B) ? (wt + (size_t)j * D) : (mt + (size_t)(j - B) * D);
        const float4* Fj4 = (const float4*)Fj;
        float a0 = 0.f, a1 = 0.f, an = 0.f;
        #pragma unroll
        for (int q = 0; q < 8; ++q) {
            const float4 v = Fj4[s + 16 * q];
            a0 += fr0[q].x * v.x + fr0[q].y * v.y + fr0[q].z * v.z + fr0[q].w * v.w;
            a1 += fr1[q].x * v.x + fr1[q].y * v.y + fr1[q].z * v.z + fr1[q].w * v.w;
            an += v.x * v.x + v.y * v.y + v.z * v.z + v.w * v.w;
        }
        a0 += __shfl_down(a0, 8, 16); a1 += __shfl_down(a1, 8, 16); an += __shfl_down(an, 8, 16);
        a0 += __shfl_down(a0, 4, 16); a1 += __shfl_down(a1, 4, 16); an += __shfl_down(an, 4, 16);
        a0 += __shfl_down(a0, 2, 16); a1 += __shfl_down(a1, 2, 16); an += __shfl_down(an, 2, 16);
        a0 += __shfl_down(a0, 1, 16); a1 += __shfl_down(a1, 1, 16); an += __shfl_down(an, 1, 16);
        if (s == 0) {
            const float d0 = fmaxf(ni0 + an - 2.f * a0, 0.f);
            const float d1 = fmaxf(ni1 + an - 2.f * a1, 0.f);
            const float lg0 = -0.5f * sqrtf(d0);
            const float lg1 = -0.5f * sqrtf(d1);
            lg_acc += lg0 + lg1;              // diag residue ~1e-2, /261k later
            const int pos = srk[j];
            const float e0 = (j == i0) ? 0.f : __expf(lg0);
            const float e1 = (j == i1) ? 0.f : __expf(lg1);
            sp0[pos] = e0; sf0[pos] = e0;
            sp1[pos] = e1; sf1[pos] = e1;
        }
    }
    __syncthreads();

    // ---- phase 2a: wave-parallel scans (no block barriers inside) ----
    if (w < 4) {
        float* arr = (w == 0) ? sp0 : (w == 1) ? sf0 : (w == 2) ? sp1 : sf1;
        float4* a4 = (float4*)arr;
        float4 u0 = a4[lane * 2], u1 = a4[lane * 2 + 1];
        float v0 = u0.x, v1 = u0.y, v2 = u0.z, v3 = u0.w;
        float v4 = u1.x, v5 = u1.y, v6 = u1.z, v7 = u1.w;
        if ((w & 1) == 0) {                    // inclusive prefix scan
            v1 += v0; v2 += v1; v3 += v2; v4 += v3; v5 += v4; v6 += v5; v7 += v6;
            float x = v7;
            #pragma unroll
            for (int off = 1; off < 64; off <<= 1) {
                const float y = __shfl_up(x, off, 64);
                if (lane >= off) x += y;
            }
            float ex = __shfl_up(x, 1, 64);
            if (lane == 0) ex = 0.f;
            v0 += ex; v1 += ex; v2 += ex; v3 += ex; v4 += ex; v5 += ex; v6 += ex; v7 += ex;
        } else {                               // inclusive suffix scan
            v6 += v7; v5 += v6; v4 += v5; v3 += v4; v2 += v3; v1 += v2; v0 += v1;
            float x = v0;
            #pragma unroll
            for (int off = 1; off < 64; off <<= 1) {
                const float y = __shfl_down(x, off, 64);
                if (lane + off < 64) x += y;
            }
            float ex = __shfl_down(x, 1, 64);
            if (lane == 63) ex = 0.f;
            v0 += ex; v1 += ex; v2 += ex; v3 += ex; v4 += ex; v5 += ex; v6 += ex; v7 += ex;
        }
        a4[lane * 2]     = make_float4(v0, v1, v2, v3);
        a4[lane * 2 + 1] = make_float4(v4, v5, v6, v7);
    }
    __syncthreads();

    // ---- phase 2b: per-k denom via two exact binary searches ----
    const int ri0 = srk[i0], ri1 = srk[i1];
    float local = lg_acc;
    #pragma unroll
    for (int p = 0; p < 2; ++p) {
        const int idx = t + p * NT;           // 0..1023
        const int row = idx >> 9;             // wave-uniform
        const int x = idx & (N - 1);
        const int ri = row ? ri1 : ri0;
        const float li = row ? li1 : li0;
        const float* SP = row ? sp1 : sp0;
        const float* SF = row ? sf1 : sf0;
        if (x != ri) {
            const float th = fabsf(li - sl[x]);
            int lo = 0, hi = ri + 1;          // left branch: weakly decreasing
            while (lo < hi) {
                const int mid = (lo + hi) >> 1;
                if (fabsf(li - sl[mid]) >= th) lo = mid + 1; else hi = mid;
            }
            const int a = lo;
            lo = ri + 1; hi = N;              // right branch: weakly increasing
            while (lo < hi) {
                const int mid = (lo + hi) >> 1;
                if (fabsf(li - sl[mid]) >= th) hi = mid; else lo = mid + 1;
            }
            const int bb = lo;
            const float denom = ((a > 0) ? SP[a - 1] : 0.f) + ((bb < N) ? SF[bb] : 0.f);
            local -= __logf(denom);
        }
    }

    // ---- block reduction + last-block finalize ----
    #pragma unroll
    for (int off = 32; off > 0; off >>= 1)
        local += __shfl_down(local, off, 64);
    if (lane == 0) sred[w] = local;
    __syncthreads();
    if (t == 0) {
        float sum = 0.f;
        #pragma unroll
        for (int k = 0; k < NT / 64; ++k) sum += sred[k];
        atomicAdd(&ws[WS_SUM], sum);          // device-scope
        __threadfence();
        const unsigned old = atomicAdd(&((unsigned*)ws)[WS_CNT], 1u);
        if (old == NBLK - 1) {                // last block: all sums visible
            __threadfence();
            const float total = atomicAdd(&ws[WS_SUM], 0.f);  // atomic read
            out[0] = -total / (float)((long)N * (N - 1));
        }
    }
}

extern "C" void kernel_launch(void* const* d_in, const int* in_sizes, int n_in,
                              void* d_out, int out_size, void* d_ws, size_t ws_size,
                              hipStream_t stream) {
    const float* wt  = (const float*)d_in[0];
    const float* mt  = (const float*)d_in[1];
    const float* lwt = (const float*)d_in[2];
    const float* lmt = (const float*)d_in[3];
    float* out = (float*)d_out;
    float* ws  = (float*)d_ws;

    rank_kernel<<<16, NT, 0, stream>>>(lwt, lmt, ws);
    rnc_main<<<NBLK, NT, 0, stream>>>(wt, mt, lwt, lmt, ws, out);
}

// Round 6
// 85.124 us; speedup vs baseline: 1.0867x; 1.0867x over previous
//
#include <hip/hip_runtime.h>

#define N 512          // n = 2*B
#define B 256
#define D 512
#define NT 512         // block size
#define NBLK (N / 2)   // 256 main blocks, 2 rows each

// ws layout (float offsets)
#define WS_SL    0           // [N] sorted labels ascending
#define WS_RANK  N           // [N] int rank of original index j
#define WS_NORM  (2 * N)     // [N] ||f16_j||^2 (fp32 accum over rounded values)
#define WS_PART  (3 * N)     // [NBLK] per-block partial sums
#define WS_FH    2048        // halves region: N*D _Float16 (512 KB), 16B-aligned

typedef _Float16 half2_t __attribute__((ext_vector_type(2)));
typedef _Float16 half4_t __attribute__((ext_vector_type(4)));

#if defined(__has_builtin) && __has_builtin(__builtin_amdgcn_fdot2)
#define FDOT2(a, b, c) __builtin_amdgcn_fdot2((a), (b), (c), false)
#else
#define FDOT2(a, b, c) ((c) + (float)(a)[0] * (float)(b)[0] + (float)(a)[1] * (float)(b)[1])
#endif

__device__ __forceinline__ half2_t bch2(unsigned int u) {
    return __builtin_bit_cast(half2_t, u);
}

// ---- kernel 1 (grid 16): label ranks + fp16 conversion + norms-of-rounded ----
__global__ __launch_bounds__(NT) void rank_conv_kernel(
    const float* __restrict__ wt, const float* __restrict__ mt,
    const float* __restrict__ lwt, const float* __restrict__ lmt,
    float* __restrict__ ws)
{
    const int t = threadIdx.x, b = blockIdx.x;
    __shared__ float slab[N];
    __shared__ int scnt[32];
    slab[t] = (t < B) ? lwt[t] : lmt[t - B];
    if (t < 32) scnt[t] = 0;
    __syncthreads();

    // rank of j = b*32 + (t&31); chunk c = t>>5 covers x in [c*32, c*32+32)
    const int jj = t & 31, j = b * 32 + jj, c = t >> 5;
    const float lj = slab[j];
    int r = 0;
    #pragma unroll 8
    for (int x = c * 32; x < c * 32 + 32; ++x) {
        const float v = slab[x];
        r += (v < lj || (v == lj && x < j)) ? 1 : 0;
    }
    atomicAdd(&scnt[jj], r);

    // convert rows [b*32, b*32+32) to fp16, norms from the rounded values
    const int row = b * 32 + (t >> 4), s16 = t & 15;
    const float* F = (row < B) ? (wt + (size_t)row * D) : (mt + (size_t)(row - B) * D);
    const float4* F4 = (const float4*)F;
    _Float16* fh = (_Float16*)(ws + WS_FH);
    half4_t* H4 = (half4_t*)(fh + (size_t)row * D);
    float nacc = 0.f;
    #pragma unroll
    for (int q = 0; q < 8; ++q) {
        const int idx = s16 + 16 * q;
        const float4 v = F4[idx];
        half4_t h;
        h[0] = (_Float16)v.x; h[1] = (_Float16)v.y;
        h[2] = (_Float16)v.z; h[3] = (_Float16)v.w;
        const float f0 = (float)h[0], f1 = (float)h[1];
        const float f2 = (float)h[2], f3 = (float)h[3];
        nacc += f0 * f0 + f1 * f1 + f2 * f2 + f3 * f3;
        H4[idx] = h;
    }
    nacc += __shfl_down(nacc, 8, 16);
    nacc += __shfl_down(nacc, 4, 16);
    nacc += __shfl_down(nacc, 2, 16);
    nacc += __shfl_down(nacc, 1, 16);
    if (s16 == 0) ws[WS_NORM + row] = nacc;

    __syncthreads();
    if (t < 32) {
        const int r2 = scnt[t], j2 = b * 32 + t;
        ws[WS_SL + r2] = slab[j2];
        ((int*)ws)[WS_RANK + j2] = r2;
    }
}

// ---- kernel 2 (grid 256): 2 rows/block, fp16 Gram + scan + search ----
__global__ __launch_bounds__(NT) void rnc_main(
    const float* __restrict__ lwt, const float* __restrict__ lmt,
    float* __restrict__ ws)
{
    const int b = blockIdx.x, i0 = 2 * b, i1 = 2 * b + 1;
    const int t = threadIdx.x;
    const int w = t >> 6, lane = t & 63, g = lane >> 4, s = lane & 15;

    __shared__ float sl[N];
    __shared__ int   srk[N];
    __shared__ float snm[N];
    __shared__ __align__(16) float sp0[N];   // row0 prefix-scan array
    __shared__ __align__(16) float sf0[N];   // row0 suffix-scan array
    __shared__ __align__(16) float sp1[N];
    __shared__ __align__(16) float sf1[N];
    __shared__ float sred[NT / 64];

    sl[t]  = ws[WS_SL + t];
    srk[t] = ((const int*)ws)[WS_RANK + t];
    snm[t] = ws[WS_NORM + t];

    // preload rows i0, i1 as fp16 (32 halfs/lane: uint4 chunks s+16q)
    const _Float16* fh = (const _Float16*)(ws + WS_FH);
    const uint4* Hi0 = (const uint4*)(fh + (size_t)i0 * D);
    const uint4* Hi1 = (const uint4*)(fh + (size_t)i1 * D);
    uint4 hr0[4], hr1[4];
    #pragma unroll
    for (int q = 0; q < 4; ++q) { hr0[q] = Hi0[s + 16 * q]; hr1[q] = Hi1[s + 16 * q]; }
    const float li0 = (i0 < B) ? lwt[i0] : lmt[i0 - B];
    const float li1 = (i1 < B) ? lwt[i1] : lmt[i1 - B];
    __syncthreads();
    const float ni0 = snm[i0], ni1 = snm[i1];

    // ---- phase 1: Gram-form distances via v_dot2_f32_f16 ----
    float lg_acc = 0.f;
    const int wg = w * 4 + g;                 // 0..31
    for (int m = 0; m < 16; ++m) {
        const int j = wg + 32 * m;
        const uint4* Hj = (const uint4*)(fh + (size_t)j * D);
        float a0 = 0.f, a1 = 0.f;
        #pragma unroll
        for (int q = 0; q < 4; ++q) {
            const uint4 v = Hj[s + 16 * q];   // 16 lanes x 16B contiguous
            a0 = FDOT2(bch2(v.x), bch2(hr0[q].x), a0);
            a0 = FDOT2(bch2(v.y), bch2(hr0[q].y), a0);
            a0 = FDOT2(bch2(v.z), bch2(hr0[q].z), a0);
            a0 = FDOT2(bch2(v.w), bch2(hr0[q].w), a0);
            a1 = FDOT2(bch2(v.x), bch2(hr1[q].x), a1);
            a1 = FDOT2(bch2(v.y), bch2(hr1[q].y), a1);
            a1 = FDOT2(bch2(v.z), bch2(hr1[q].z), a1);
            a1 = FDOT2(bch2(v.w), bch2(hr1[q].w), a1);
        }
        a0 += __shfl_down(a0, 8, 16); a1 += __shfl_down(a1, 8, 16);
        a0 += __shfl_down(a0, 4, 16); a1 += __shfl_down(a1, 4, 16);
        a0 += __shfl_down(a0, 2, 16); a1 += __shfl_down(a1, 2, 16);
        a0 += __shfl_down(a0, 1, 16); a1 += __shfl_down(a1, 1, 16);
        if (s == 0) {
            const float nj = snm[j];
            const float d0 = fmaxf(ni0 + nj - 2.f * a0, 0.f);
            const float d1 = fmaxf(ni1 + nj - 2.f * a1, 0.f);
            const float lg0 = -0.5f * sqrtf(d0);
            const float lg1 = -0.5f * sqrtf(d1);
            if (j != i0) lg_acc += lg0;       // reference sums off-diag logits only
            if (j != i1) lg_acc += lg1;
            const int pos = srk[j];
            const float e0 = (j == i0) ? 0.f : __expf(lg0);
            const float e1 = (j == i1) ? 0.f : __expf(lg1);
            sp0[pos] = e0; sf0[pos] = e0;
            sp1[pos] = e1; sf1[pos] = e1;
        }
    }
    __syncthreads();

    // ---- phase 2a: wave-parallel scans (no block barriers inside) ----
    if (w < 4) {
        float* arr = (w == 0) ? sp0 : (w == 1) ? sf0 : (w == 2) ? sp1 : sf1;
        float4* a4 = (float4*)arr;
        float4 u0 = a4[lane * 2], u1 = a4[lane * 2 + 1];
        float v0 = u0.x, v1 = u0.y, v2 = u0.z, v3 = u0.w;
        float v4 = u1.x, v5 = u1.y, v6 = u1.z, v7 = u1.w;
        if ((w & 1) == 0) {                    // inclusive prefix scan
            v1 += v0; v2 += v1; v3 += v2; v4 += v3; v5 += v4; v6 += v5; v7 += v6;
            float x = v7;
            #pragma unroll
            for (int off = 1; off < 64; off <<= 1) {
                const float y = __shfl_up(x, off, 64);
                if (lane >= off) x += y;
            }
            float ex = __shfl_up(x, 1, 64);
            if (lane == 0) ex = 0.f;
            v0 += ex; v1 += ex; v2 += ex; v3 += ex; v4 += ex; v5 += ex; v6 += ex; v7 += ex;
        } else {                               // inclusive suffix scan
            v6 += v7; v5 += v6; v4 += v5; v3 += v4; v2 += v3; v1 += v2; v0 += v1;
            float x = v0;
            #pragma unroll
            for (int off = 1; off < 64; off <<= 1) {
                const float y = __shfl_down(x, off, 64);
                if (lane + off < 64) x += y;
            }
            float ex = __shfl_down(x, 1, 64);
            if (lane == 63) ex = 0.f;
            v0 += ex; v1 += ex; v2 += ex; v3 += ex; v4 += ex; v5 += ex; v6 += ex; v7 += ex;
        }
        a4[lane * 2]     = make_float4(v0, v1, v2, v3);
        a4[lane * 2 + 1] = make_float4(v4, v5, v6, v7);
    }
    __syncthreads();

    // ---- phase 2b: per-k denom via two exact binary searches ----
    const int ri0 = srk[i0], ri1 = srk[i1];
    float local = lg_acc;
    #pragma unroll
    for (int p = 0; p < 2; ++p) {
        const int idx = t + p * NT;           // 0..1023
        const int row = idx >> 9;             // wave-uniform
        const int x = idx & (N - 1);
        const int ri = row ? ri1 : ri0;
        const float li = row ? li1 : li0;
        const float* SP = row ? sp1 : sp0;
        const float* SF = row ? sf1 : sf0;
        if (x != ri) {
            const float th = fabsf(li - sl[x]);
            int lo = 0, hi = ri + 1;          // left branch: weakly decreasing
            while (lo < hi) {
                const int mid = (lo + hi) >> 1;
                if (fabsf(li - sl[mid]) >= th) lo = mid + 1; else hi = mid;
            }
            const int a = lo;
            lo = ri + 1; hi = N;              // right branch: weakly increasing
            while (lo < hi) {
                const int mid = (lo + hi) >> 1;
                if (fabsf(li - sl[mid]) >= th) hi = mid; else lo = mid + 1;
            }
            const int bb = lo;
            const float denom = ((a > 0) ? SP[a - 1] : 0.f) + ((bb < N) ? SF[bb] : 0.f);
            local -= __logf(denom);
        }
    }

    // ---- block reduction, plain store ----
    #pragma unroll
    for (int off = 32; off > 0; off >>= 1)
        local += __shfl_down(local, off, 64);
    if (lane == 0) sred[w] = local;
    __syncthreads();
    if (t == 0) {
        float sum = 0.f;
        #pragma unroll
        for (int k = 0; k < NT / 64; ++k) sum += sred[k];
        ws[WS_PART + b] = sum;
    }
}

// ---- kernel 3: reduce 256 partials + finalize ----
__global__ __launch_bounds__(NBLK) void rnc_finalize(
    const float* __restrict__ ws, float* __restrict__ out)
{
    const int t = threadIdx.x;
    __shared__ float sred[NBLK / 64];
    float v = ws[WS_PART + t];
    #pragma unroll
    for (int off = 32; off > 0; off >>= 1)
        v += __shfl_down(v, off, 64);
    if ((t & 63) == 0) sred[t >> 6] = v;
    __syncthreads();
    if (t == 0) {
        float sum = 0.f;
        #pragma unroll
        for (int k = 0; k < NBLK / 64; ++k) sum += sred[k];
        out[0] = -sum / (float)((long)N * (N - 1));
    }
}

extern "C" void kernel_launch(void* const* d_in, const int* in_sizes, int n_in,
                              void* d_out, int out_size, void* d_ws, size_t ws_size,
                              hipStream_t stream) {
    const float* wt  = (const float*)d_in[0];
    const float* mt  = (const float*)d_in[1];
    const float* lwt = (const float*)d_in[2];
    const float* lmt = (const float*)d_in[3];
    float* out = (float*)d_out;
    float* ws  = (float*)d_ws;

    rank_conv_kernel<<<16, NT, 0, stream>>>(wt, mt, lwt, lmt, ws);
    rnc_main<<<NBLK, NT, 0, stream>>>(lwt, lmt, ws);
    rnc_finalize<<<1, NBLK, 0, stream>>>(ws, out);
}

// Round 7
// 83.218 us; speedup vs baseline: 1.1116x; 1.0229x over previous
//
#include <hip/hip_runtime.h>

#define N 512          // n = 2*B
#define B 256
#define D 512
#define NT 512         // block size
#define NBLK (N / 2)   // 256 main blocks, 2 rows each

// ws layout (float offsets)
#define WS_SL    0           // [N] sorted labels ascending
#define WS_NORM  512         // [N] ||f||^2 indexed by sorted position
#define WS_PART  1024        // [NBLK] per-block partial sums
#define WS_FS    2048        // [N*D] features permuted into sorted-label order

// ---- kernel 1 (grid 16): ranks + permute rows into sorted order + norms ----
__global__ __launch_bounds__(NT) void sort_rows_kernel(
    const float* __restrict__ wt, const float* __restrict__ mt,
    const float* __restrict__ lwt, const float* __restrict__ lmt,
    float* __restrict__ ws)
{
    const int t = threadIdx.x, b = blockIdx.x;
    __shared__ float slab[N];
    __shared__ int scnt[32];
    slab[t] = (t < B) ? lwt[t] : lmt[t - B];
    if (t < 32) scnt[t] = 0;
    __syncthreads();

    // rank of j = b*32 + (t&31); chunk c = t>>5 covers x in [c*32, c*32+32)
    const int jj = t & 31, j = b * 32 + jj, c = t >> 5;
    const float lj = slab[j];
    int r = 0;
    #pragma unroll 8
    for (int x = c * 32; x < c * 32 + 32; ++x) {
        const float v = slab[x];   // <=2 distinct addrs per wave: conflict-free
        r += (v < lj || (v == lj && x < j)) ? 1 : 0;
    }
    atomicAdd(&scnt[jj], r);
    __syncthreads();

    if (t < 32)
        ws[WS_SL + scnt[t]] = slab[b * 32 + t];

    // permute rows [b*32, b*32+32) to sorted positions, norms in same pass
    const int row = b * 32 + (t >> 4), s16 = t & 15;
    const int rr = scnt[t >> 4];              // rank (sorted position) of row
    const float* F = (row < B) ? (wt + (size_t)row * D) : (mt + (size_t)(row - B) * D);
    const float4* F4 = (const float4*)F;
    float4* Dst = (float4*)(ws + WS_FS + (size_t)rr * D);
    float nacc = 0.f;
    #pragma unroll
    for (int q = 0; q < 8; ++q) {
        const int idx = s16 + 16 * q;
        const float4 v = F4[idx];
        nacc += v.x * v.x + v.y * v.y + v.z * v.z + v.w * v.w;
        Dst[idx] = v;                         // coalesced 256B per 16-lane group
    }
    nacc += __shfl_down(nacc, 8, 16);
    nacc += __shfl_down(nacc, 4, 16);
    nacc += __shfl_down(nacc, 2, 16);
    nacc += __shfl_down(nacc, 1, 16);
    if (s16 == 0) ws[WS_NORM + rr] = nacc;
}

// ---- kernel 2 (grid 256): rows are pre-sorted; 2 rows/block ----
__global__ __launch_bounds__(NT) void rnc_main(
    float* __restrict__ ws)
{
    const int b = blockIdx.x, i0 = 2 * b, i1 = 2 * b + 1;  // sorted positions
    const int t = threadIdx.x;
    const int w = t >> 6, lane = t & 63, g = lane >> 4, s = lane & 15;

    __shared__ float sl[N];
    __shared__ float snm[N];
    __shared__ __align__(16) float sp0[N];   // row0 prefix-scan array
    __shared__ __align__(16) float sf0[N];   // row0 suffix-scan array
    __shared__ __align__(16) float sp1[N];
    __shared__ __align__(16) float sf1[N];
    __shared__ float sred[NT / 64];

    sl[t]  = ws[WS_SL + t];
    snm[t] = ws[WS_NORM + t];

    // preload sorted rows i0, i1 (32 floats each per lane, chunk = s + 16q)
    const float* Fs = ws + WS_FS;
    const float4* Fi04 = (const float4*)(Fs + (size_t)i0 * D);
    const float4* Fi14 = (const float4*)(Fs + (size_t)i1 * D);
    float4 fr0[8], fr1[8];
    #pragma unroll
    for (int q = 0; q < 8; ++q) { fr0[q] = Fi04[s + 16 * q]; fr1[q] = Fi14[s + 16 * q]; }
    __syncthreads();
    const float li0 = sl[i0], li1 = sl[i1];
    const float ni0 = snm[i0], ni1 = snm[i1];

    // ---- phase 1: Gram-form distances, sequential e-writes (no scatter) ----
    float lg_acc = 0.f;
    const int wg = w * 4 + g;                 // 0..31
    for (int m = 0; m < 16; ++m) {
        const int j = wg + 32 * m;
        const float4* Fj4 = (const float4*)(Fs + (size_t)j * D);
        float a0 = 0.f, a1 = 0.f;
        #pragma unroll
        for (int q = 0; q < 8; ++q) {
            const float4 v = Fj4[s + 16 * q];
            a0 += fr0[q].x * v.x + fr0[q].y * v.y + fr0[q].z * v.z + fr0[q].w * v.w;
            a1 += fr1[q].x * v.x + fr1[q].y * v.y + fr1[q].z * v.z + fr1[q].w * v.w;
        }
        a0 += __shfl_down(a0, 8, 16); a1 += __shfl_down(a1, 8, 16);
        a0 += __shfl_down(a0, 4, 16); a1 += __shfl_down(a1, 4, 16);
        a0 += __shfl_down(a0, 2, 16); a1 += __shfl_down(a1, 2, 16);
        a0 += __shfl_down(a0, 1, 16); a1 += __shfl_down(a1, 1, 16);
        if (s == 0) {
            const float nj = snm[j];
            const float d0 = fmaxf(ni0 + nj - 2.f * a0, 0.f);
            const float d1 = fmaxf(ni1 + nj - 2.f * a1, 0.f);
            const float lg0 = -0.5f * sqrtf(d0);
            const float lg1 = -0.5f * sqrtf(d1);
            if (j != i0) lg_acc += lg0;       // exclude diagonal residue
            if (j != i1) lg_acc += lg1;
            const float e0 = (j == i0) ? 0.f : __expf(lg0);
            const float e1 = (j == i1) ? 0.f : __expf(lg1);
            sp0[j] = e0; sf0[j] = e0;
            sp1[j] = e1; sf1[j] = e1;
        }
    }
    __syncthreads();

    // ---- phase 2a: wave-parallel scans (no block barriers inside) ----
    if (w < 4) {
        float* arr = (w == 0) ? sp0 : (w == 1) ? sf0 : (w == 2) ? sp1 : sf1;
        float4* a4 = (float4*)arr;
        float4 u0 = a4[lane * 2], u1 = a4[lane * 2 + 1];
        float v0 = u0.x, v1 = u0.y, v2 = u0.z, v3 = u0.w;
        float v4 = u1.x, v5 = u1.y, v6 = u1.z, v7 = u1.w;
        if ((w & 1) == 0) {                    // inclusive prefix scan
            v1 += v0; v2 += v1; v3 += v2; v4 += v3; v5 += v4; v6 += v5; v7 += v6;
            float x = v7;
            #pragma unroll
            for (int off = 1; off < 64; off <<= 1) {
                const float y = __shfl_up(x, off, 64);
                if (lane >= off) x += y;
            }
            float ex = __shfl_up(x, 1, 64);
            if (lane == 0) ex = 0.f;
            v0 += ex; v1 += ex; v2 += ex; v3 += ex; v4 += ex; v5 += ex; v6 += ex; v7 += ex;
        } else {                               // inclusive suffix scan
            v6 += v7; v5 += v6; v4 += v5; v3 += v4; v2 += v3; v1 += v2; v0 += v1;
            float x = v0;
            #pragma unroll
            for (int off = 1; off < 64; off <<= 1) {
                const float y = __shfl_down(x, off, 64);
                if (lane + off < 64) x += y;
            }
            float ex = __shfl_down(x, 1, 64);
            if (lane == 63) ex = 0.f;
            v0 += ex; v1 += ex; v2 += ex; v3 += ex; v4 += ex; v5 += ex; v6 += ex; v7 += ex;
        }
        a4[lane * 2]     = make_float4(v0, v1, v2, v3);
        a4[lane * 2 + 1] = make_float4(v4, v5, v6, v7);
    }
    __syncthreads();

    // ---- phase 2b: per-k denom via two exact binary searches (ri == i) ----
    float local = lg_acc;
    #pragma unroll
    for (int p = 0; p < 2; ++p) {
        const int idx = t + p * NT;           // 0..1023
        const int row = idx >> 9;             // wave-uniform
        const int x = idx & (N - 1);          // sorted position of k
        const int ri = row ? i1 : i0;
        const float li = row ? li1 : li0;
        const float* SP = row ? sp1 : sp0;
        const float* SF = row ? sf1 : sf0;
        if (x != ri) {
            const float th = fabsf(li - sl[x]);
            int lo = 0, hi = ri + 1;          // left branch: weakly decreasing
            while (lo < hi) {
                const int mid = (lo + hi) >> 1;
                if (fabsf(li - sl[mid]) >= th) lo = mid + 1; else hi = mid;
            }
            const int a = lo;
            lo = ri + 1; hi = N;              // right branch: weakly increasing
            while (lo < hi) {
                const int mid = (lo + hi) >> 1;
                if (fabsf(li - sl[mid]) >= th) hi = mid; else lo = mid + 1;
            }
            const int bb = lo;
            const float denom = ((a > 0) ? SP[a - 1] : 0.f) + ((bb < N) ? SF[bb] : 0.f);
            local -= __logf(denom);
        }
    }

    // ---- block reduction, plain store ----
    #pragma unroll
    for (int off = 32; off > 0; off >>= 1)
        local += __shfl_down(local, off, 64);
    if (lane == 0) sred[w] = local;
    __syncthreads();
    if (t == 0) {
        float sum = 0.f;
        #pragma unroll
        for (int k = 0; k < NT / 64; ++k) sum += sred[k];
        ws[WS_PART + b] = sum;
    }
}

// ---- kernel 3: reduce 256 partials + finalize ----
__global__ __launch_bounds__(NBLK) void rnc_finalize(
    const float* __restrict__ ws, float* __restrict__ out)
{
    const int t = threadIdx.x;
    __shared__ float sred[NBLK / 64];
    float v = ws[WS_PART + t];
    #pragma unroll
    for (int off = 32; off > 0; off >>= 1)
        v += __shfl_down(v, off, 64);
    if ((t & 63) == 0) sred[t >> 6] = v;
    __syncthreads();
    if (t == 0) {
        float sum = 0.f;
        #pragma unroll
        for (int k = 0; k < NBLK / 64; ++k) sum += sred[k];
        out[0] = -sum / (float)((long)N * (N - 1));
    }
}

extern "C" void kernel_launch(void* const* d_in, const int* in_sizes, int n_in,
                              void* d_out, int out_size, void* d_ws, size_t ws_size,
                              hipStream_t stream) {
    const float* wt  = (const float*)d_in[0];
    const float* mt  = (const float*)d_in[1];
    const float* lwt = (const float*)d_in[2];
    const float* lmt = (const float*)d_in[3];
    float* out = (float*)d_out;
    float* ws  = (float*)d_ws;

    sort_rows_kernel<<<16, NT, 0, stream>>>(wt, mt, lwt, lmt, ws);
    rnc_main<<<NBLK, NT, 0, stream>>>(ws);
    rnc_finalize<<<1, NBLK, 0, stream>>>(ws, out);
}

// Round 8
// 74.841 us; speedup vs baseline: 1.2360x; 1.1119x over previous
//
#include <hip/hip_runtime.h>

#define N 512          // n = 2*B
#define B 256
#define D 512
#define NT 512         // block size for sort/main
#define NBLK (N / 2)   // 256 main blocks, 2 rows each

// ws layout (float offsets)
#define WS_SL    0                    // [N] sorted labels ascending
#define WS_NORM  512                  // [N] ||f16||^2 (fp32) by sorted position
#define WS_PART  1024                 // [NBLK] per-block partial sums
#define WS_FH    2048                 // N*D _Float16 sorted features (512 KB)
#define WS_G     (2048 + (N * D) / 2) // [N*N] fp32 Gram matrix (1 MB)

typedef _Float16 half4_t  __attribute__((ext_vector_type(4)));
typedef _Float16 half8_t  __attribute__((ext_vector_type(8)));
typedef float    f32x4    __attribute__((ext_vector_type(4)));

// ---- kernel 1 (grid 16): ranks + permute rows to sorted order as fp16 ----
__global__ __launch_bounds__(NT) void sort_rows_kernel(
    const float* __restrict__ wt, const float* __restrict__ mt,
    const float* __restrict__ lwt, const float* __restrict__ lmt,
    float* __restrict__ ws)
{
    const int t = threadIdx.x, b = blockIdx.x;
    __shared__ float slab[N];
    __shared__ int scnt[32];
    slab[t] = (t < B) ? lwt[t] : lmt[t - B];
    if (t < 32) scnt[t] = 0;
    __syncthreads();

    // rank of j = b*32 + (t&31); chunk c = t>>5 covers x in [c*32, c*32+32)
    const int jj = t & 31, j = b * 32 + jj, c = t >> 5;
    const float lj = slab[j];
    int r = 0;
    #pragma unroll 8
    for (int x = c * 32; x < c * 32 + 32; ++x) {
        const float v = slab[x];
        r += (v < lj || (v == lj && x < j)) ? 1 : 0;
    }
    atomicAdd(&scnt[jj], r);
    __syncthreads();

    if (t < 32)
        ws[WS_SL + scnt[t]] = slab[b * 32 + t];

    // permute rows [b*32, b*32+32) into sorted fp16; norms of rounded values
    const int row = b * 32 + (t >> 4), s16 = t & 15;
    const int rr = scnt[t >> 4];              // sorted position of row
    const float* F = (row < B) ? (wt + (size_t)row * D) : (mt + (size_t)(row - B) * D);
    const float4* F4 = (const float4*)F;
    half4_t* Dst = (half4_t*)((_Float16*)(ws + WS_FH) + (size_t)rr * D);
    float nacc = 0.f;
    #pragma unroll
    for (int q = 0; q < 8; ++q) {
        const int idx = s16 + 16 * q;
        const float4 v = F4[idx];
        half4_t h;
        h[0] = (_Float16)v.x; h[1] = (_Float16)v.y;
        h[2] = (_Float16)v.z; h[3] = (_Float16)v.w;
        const float f0 = (float)h[0], f1 = (float)h[1];
        const float f2 = (float)h[2], f3 = (float)h[3];
        nacc += f0 * f0 + f1 * f1 + f2 * f2 + f3 * f3;
        Dst[idx] = h;                         // 8B/lane, coalesced per 16-lane group
    }
    nacc += __shfl_down(nacc, 8, 16);
    nacc += __shfl_down(nacc, 4, 16);
    nacc += __shfl_down(nacc, 2, 16);
    nacc += __shfl_down(nacc, 1, 16);
    if (s16 == 0) ws[WS_NORM + rr] = nacc;
}

// ---- kernel 2 (grid 256 x 256thr): MFMA Gram G = F16 * F16^T, fp32 out ----
__global__ __launch_bounds__(256) void gram_kernel(float* __restrict__ ws)
{
    const int lane = threadIdx.x & 63;
    const int wid  = blockIdx.x * 4 + (threadIdx.x >> 6);   // 0..1023
    const int ti = wid >> 5, tj = wid & 31;                 // 16x16 tile coords
    const int quad = lane >> 4, m = lane & 15;

    const _Float16* Fh = (const _Float16*)(ws + WS_FH);
    const _Float16* Arow = Fh + (size_t)(ti * 16 + m) * D + quad * 8;
    const _Float16* Brow = Fh + (size_t)(tj * 16 + m) * D + quad * 8;

    f32x4 acc = {0.f, 0.f, 0.f, 0.f};
    #pragma unroll
    for (int k0 = 0; k0 < D; k0 += 32) {
        const half8_t a = *(const half8_t*)(Arow + k0);   // A[m][quad*8+j]
        const half8_t b = *(const half8_t*)(Brow + k0);   // B[k=quad*8+j][n=m]
        acc = __builtin_amdgcn_mfma_f32_16x16x32_f16(a, b, acc, 0, 0, 0);
    }
    // C/D layout: col = lane&15, row = quad*4 + reg   (Gram symmetric ->
    // a row/col transposition here would be value-identical anyway)
    float* G = ws + WS_G;
    const int col = tj * 16 + m;
    #pragma unroll
    for (int rg = 0; rg < 4; ++rg)
        G[(size_t)(ti * 16 + quad * 4 + rg) * N + col] = acc[rg];
}

// ---- kernel 3 (grid 256): 2 rows/block; e from G, scan, binsearch ----
__global__ __launch_bounds__(NT) void rnc_main(float* __restrict__ ws)
{
    const int b = blockIdx.x, i0 = 2 * b, i1 = 2 * b + 1;  // sorted positions
    const int t = threadIdx.x;
    const int w = t >> 6, lane = t & 63;

    __shared__ float sl[N];
    __shared__ float snm[N];
    __shared__ __align__(16) float sp0[N];
    __shared__ __align__(16) float sf0[N];
    __shared__ __align__(16) float sp1[N];
    __shared__ __align__(16) float sf1[N];
    __shared__ float sred[NT / 64];

    sl[t]  = ws[WS_SL + t];
    snm[t] = ws[WS_NORM + t];
    __syncthreads();
    const float li0 = sl[i0], li1 = sl[i1];
    const float ni0 = snm[i0], ni1 = snm[i1];

    // ---- phase 1: e from precomputed Gram rows (coalesced 4 KB total) ----
    const float* G = ws + WS_G;
    const float g0 = G[(size_t)i0 * N + t];
    const float g1 = G[(size_t)i1 * N + t];
    const float d0 = fmaxf(ni0 + snm[t] - 2.f * g0, 0.f);
    const float d1 = fmaxf(ni1 + snm[t] - 2.f * g1, 0.f);
    const float lg0 = -0.5f * sqrtf(d0);
    const float lg1 = -0.5f * sqrtf(d1);
    float lg_acc = 0.f;
    if (t != i0) lg_acc += lg0;
    if (t != i1) lg_acc += lg1;
    const float e0 = (t == i0) ? 0.f : __expf(lg0);
    const float e1 = (t == i1) ? 0.f : __expf(lg1);
    sp0[t] = e0; sf0[t] = e0;
    sp1[t] = e1; sf1[t] = e1;
    __syncthreads();

    // ---- phase 2a: wave-parallel scans (no block barriers inside) ----
    if (w < 4) {
        float* arr = (w == 0) ? sp0 : (w == 1) ? sf0 : (w == 2) ? sp1 : sf1;
        float4* a4 = (float4*)arr;
        float4 u0 = a4[lane * 2], u1 = a4[lane * 2 + 1];
        float v0 = u0.x, v1 = u0.y, v2 = u0.z, v3 = u0.w;
        float v4 = u1.x, v5 = u1.y, v6 = u1.z, v7 = u1.w;
        if ((w & 1) == 0) {                    // inclusive prefix scan
            v1 += v0; v2 += v1; v3 += v2; v4 += v3; v5 += v4; v6 += v5; v7 += v6;
            float x = v7;
            #pragma unroll
            for (int off = 1; off < 64; off <<= 1) {
                const float y = __shfl_up(x, off, 64);
                if (lane >= off) x += y;
            }
            float ex = __shfl_up(x, 1, 64);
            if (lane == 0) ex = 0.f;
            v0 += ex; v1 += ex; v2 += ex; v3 += ex; v4 += ex; v5 += ex; v6 += ex; v7 += ex;
        } else {                               // inclusive suffix scan
            v6 += v7; v5 += v6; v4 += v5; v3 += v4; v2 += v3; v1 += v2; v0 += v1;
            float x = v0;
            #pragma unroll
            for (int off = 1; off < 64; off <<= 1) {
                const float y = __shfl_down(x, off, 64);
                if (lane + off < 64) x += y;
            }
            float ex = __shfl_down(x, 1, 64);
            if (lane == 63) ex = 0.f;
            v0 += ex; v1 += ex; v2 += ex; v3 += ex; v4 += ex; v5 += ex; v6 += ex; v7 += ex;
        }
        a4[lane * 2]     = make_float4(v0, v1, v2, v3);
        a4[lane * 2 + 1] = make_float4(v4, v5, v6, v7);
    }
    __syncthreads();

    // ---- phase 2b: per-k denom via two exact binary searches (ri == i) ----
    float local = lg_acc;
    #pragma unroll
    for (int p = 0; p < 2; ++p) {
        const int x = t;                      // sorted position of k
        const int ri = p ? i1 : i0;
        const float li = p ? li1 : li0;
        const float* SP = p ? sp1 : sp0;
        const float* SF = p ? sf1 : sf0;
        if (x != ri) {
            const float th = fabsf(li - sl[x]);
            int lo = 0, hi = ri + 1;          // left branch: weakly decreasing
            while (lo < hi) {
                const int mid = (lo + hi) >> 1;
                if (fabsf(li - sl[mid]) >= th) lo = mid + 1; else hi = mid;
            }
            const int a = lo;
            lo = ri + 1; hi = N;              // right branch: weakly increasing
            while (lo < hi) {
                const int mid = (lo + hi) >> 1;
                if (fabsf(li - sl[mid]) >= th) hi = mid; else lo = mid + 1;
            }
            const int bb = lo;
            const float denom = ((a > 0) ? SP[a - 1] : 0.f) + ((bb < N) ? SF[bb] : 0.f);
            local -= __logf(denom);
        }
    }

    // ---- block reduction, plain store ----
    #pragma unroll
    for (int off = 32; off > 0; off >>= 1)
        local += __shfl_down(local, off, 64);
    if (lane == 0) sred[w] = local;
    __syncthreads();
    if (t == 0) {
        float sum = 0.f;
        #pragma unroll
        for (int k = 0; k < NT / 64; ++k) sum += sred[k];
        ws[WS_PART + b] = sum;
    }
}

// ---- kernel 4: reduce 256 partials + finalize ----
__global__ __launch_bounds__(NBLK) void rnc_finalize(
    const float* __restrict__ ws, float* __restrict__ out)
{
    const int t = threadIdx.x;
    __shared__ float sred[NBLK / 64];
    float v = ws[WS_PART + t];
    #pragma unroll
    for (int off = 32; off > 0; off >>= 1)
        v += __shfl_down(v, off, 64);
    if ((t & 63) == 0) sred[t >> 6] = v;
    __syncthreads();
    if (t == 0) {
        float sum = 0.f;
        #pragma unroll
        for (int k = 0; k < NBLK / 64; ++k) sum += sred[k];
        out[0] = -sum / (float)((long)N * (N - 1));
    }
}

extern "C" void kernel_launch(void* const* d_in, const int* in_sizes, int n_in,
                              void* d_out, int out_size, void* d_ws, size_t ws_size,
                              hipStream_t stream) {
    const float* wt  = (const float*)d_in[0];
    const float* mt  = (const float*)d_in[1];
    const float* lwt = (const float*)d_in[2];
    const float* lmt = (const float*)d_in[3];
    float* out = (float*)d_out;
    float* ws  = (float*)d_ws;

    sort_rows_kernel<<<16, NT, 0, stream>>>(wt, mt, lwt, lmt, ws);
    gram_kernel<<<256, 256, 0, stream>>>(ws);
    rnc_main<<<NBLK, NT, 0, stream>>>(ws);
    rnc_finalize<<<1, NBLK, 0, stream>>>(ws, out);
}